// Round 13
// baseline (102.116 us; speedup 1.0000x reference)
//
#include <hip/hip_runtime.h>
#include <math.h>

// Attention1D: B=4, L=4096, C=F=64, fp32 in/out.
// scores=(QK^T)/8; softmax over QUERY axis; out = P@V + x = E@(diag(rl)V) + x.
// v13: k_out = r12 single-buffer no-barrier skeleton at 32q/block, grid 512,
// launch_bounds(512,4) -> 2 blocks/CU = 4 waves/SIMD (occupancy was the wall:
// k_stats runs 3x our staging rate at 4 waves/SIMD). setprio dropped in k_out.

#define BB 4
#define LL 4096
#define CC 64
#define C2 0.18033688011112042f  // 0.125 * log2(e)

typedef __attribute__((ext_vector_type(8)))  short bf16x8;
typedef __attribute__((ext_vector_type(4)))  float f32x4;
typedef __attribute__((ext_vector_type(16))) float f32x16;
typedef __attribute__((ext_vector_type(4)))  unsigned int u32x4;

#define MFMA16(a, b, c) __builtin_amdgcn_mfma_f32_16x16x32_bf16(a, b, c, 0, 0, 0)
#define MFMA32(a, b, c) __builtin_amdgcn_mfma_f32_32x32x16_bf16(a, b, c, 0, 0, 0)
#define EXP2(x) __builtin_amdgcn_exp2f(x)

#define GLD4(dst, voff, base, imm) \
    asm volatile("global_load_dwordx4 %0, %1, %2 offset:%c3" \
                 : "=v"(dst) : "v"(voff), "s"(base), "i"(imm))
#define WAITVM0() asm volatile("s_waitcnt vmcnt(0)" ::: "memory")
#define SBAR() __builtin_amdgcn_sched_barrier(0)
#define PRIO(n) __builtin_amdgcn_s_setprio(n)

static __device__ __forceinline__ bf16x8 asbf(u32x4 v) {
    union { u32x4 a; bf16x8 b; } u; u.a = v; return u.b;
}
static __device__ __forceinline__ unsigned short f2bf(float f) {
    union { float f; unsigned u; } v; v.f = f;
    unsigned r = v.u + 0x7FFFu + ((v.u >> 16) & 1u);
    return (unsigned short)(r >> 16);
}
static __device__ __forceinline__ float bf2f(unsigned short h) {
    union { unsigned u; float f; } v; v.u = ((unsigned)h) << 16; return v.f;
}
static __device__ __forceinline__ bf16x8 pack8(float4 a, float4 b) {
    bf16x8 r;
    r[0] = (short)f2bf(a.x); r[1] = (short)f2bf(a.y);
    r[2] = (short)f2bf(a.z); r[3] = (short)f2bf(a.w);
    r[4] = (short)f2bf(b.x); r[5] = (short)f2bf(b.y);
    r[6] = (short)f2bf(b.z); r[7] = (short)f2bf(b.w);
    return r;
}
static __device__ __forceinline__ unsigned cvtpk(float lo, float hi) {
    unsigned r;
    asm("v_cvt_pk_bf16_f32 %0, %1, %2" : "=v"(r) : "v"(lo), "v"(hi));
    return r;
}
static __device__ __forceinline__ bf16x8 lds_frag(const unsigned short* p) {
    union { uint2 u[2]; bf16x8 b; } t;
    t.u[0] = *(const uint2*)(p);
    t.u[1] = *(const uint2*)(p + 4);
    return t.b;
}
static __device__ __forceinline__ void lds_put(unsigned short* p, u32x4 v) {
    *(uint2*)(p)     = make_uint2(v[0], v[1]);
    *(uint2*)(p + 4) = make_uint2(v[2], v[3]);
}

// ---------------- K1: projections via MFMA -> bf16 Q, K, V-tiles ----------------
__global__ __launch_bounds__(512) void k_qkv(
    const float* __restrict__ x,
    const float* __restrict__ Wq, const float* __restrict__ bq,
    const float* __restrict__ Wk, const float* __restrict__ bk,
    const float* __restrict__ Wv, const float* __restrict__ bv,
    unsigned short* __restrict__ Qb, unsigned short* __restrict__ Kb,
    unsigned short* __restrict__ Vt)
{
    __shared__ float Wl[64 * 64];
    __shared__ unsigned short ldsV[64 * 72];
    const int bid = blockIdx.x;
    const int mat = bid % 3;          // 0:Q 1:K 2:V
    const int r0 = (bid / 3) * 64;
    const int tid = threadIdx.x, w = tid >> 6, lane = tid & 63;
    const int c = lane & 15, g = lane >> 4;
    const int rw = (w >> 1) * 16;
    const int c0 = (w & 1) * 32;

    const float* W  = (mat == 0) ? Wq : (mat == 1) ? Wk : Wv;
    const float* bs = (mat == 0) ? bq : (mat == 1) ? bk : bv;

    {   // coalesced W stage
        const float4* wsrc = (const float4*)W;
        float4* wdst = (float4*)Wl;
        wdst[tid] = wsrc[tid];
        wdst[tid + 512] = wsrc[tid + 512];
    }

    const float* xr = x + (size_t)(r0 + rw + c) * CC;
    const bf16x8 ax0 = pack8(((const float4*)xr)[2 * g], ((const float4*)xr)[2 * g + 1]);
    const bf16x8 ax1 = pack8(((const float4*)xr)[8 + 2 * g], ((const float4*)xr)[8 + 2 * g + 1]);
    __syncthreads();

    f32x4 acc0 = {0.f, 0.f, 0.f, 0.f}, acc1 = {0.f, 0.f, 0.f, 0.f};
    {
        const int col = c0 + c;
        bf16x8 b0, b1;
        #pragma unroll
        for (int j = 0; j < 8; ++j) {
            b0[j] = (short)f2bf(Wl[(8 * g + j) * 64 + col]);
            b1[j] = (short)f2bf(Wl[(32 + 8 * g + j) * 64 + col]);
        }
        acc0 = MFMA16(ax0, b0, acc0); acc0 = MFMA16(ax1, b1, acc0);
    }
    {
        const int col = c0 + 16 + c;
        bf16x8 b0, b1;
        #pragma unroll
        for (int j = 0; j < 8; ++j) {
            b0[j] = (short)f2bf(Wl[(8 * g + j) * 64 + col]);
            b1[j] = (short)f2bf(Wl[(32 + 8 * g + j) * 64 + col]);
        }
        acc1 = MFMA16(ax0, b0, acc1); acc1 = MFMA16(ax1, b1, acc1);
    }
    const float bias0 = bs[c0 + c], bias1 = bs[c0 + 16 + c];

    if (mat < 2) {
        unsigned short* dst = (mat == 0) ? Qb : Kb;
        #pragma unroll
        for (int r = 0; r < 4; ++r) {
            const size_t row = (size_t)(r0 + rw + 4 * g + r) * CC;
            dst[row + c0 + c]      = f2bf(acc0[r] + bias0);
            dst[row + c0 + 16 + c] = f2bf(acc1[r] + bias1);
        }
    } else {
        #pragma unroll
        for (int r = 0; r < 4; ++r) {
            const int rowin = rw + 4 * g + r;     // k within 64-row group
            ldsV[(c0 + c) * 72 + rowin]      = f2bf(acc0[r] + bias0);
            ldsV[(c0 + 16 + c) * 72 + rowin] = f2bf(acc1[r] + bias1);
        }
        __syncthreads();
        // Vt[b][kt32][f][kin32]: two 4KB tiles per block, fully contiguous
        const int b = r0 >> 12, ktb = (r0 & 4095) >> 5;
        const int h = tid >> 8, f = (tid >> 2) & 63, ch = tid & 3;
        *(uint4*)(Vt + ((size_t)(b * 128 + ktb + h) * 64 + f) * 32 + ch * 8)
            = *(const uint4*)(ldsV + f * 72 + h * 32 + ch * 8);
    }
}

// ---------------- K2: column sums -> rescale V-tiles in place ----------------
// (unchanged from v11/v12)
__global__ __launch_bounds__(512, 4) void k_stats(
    const unsigned short* __restrict__ Qb, const unsigned short* __restrict__ Kb,
    unsigned short* __restrict__ Vt)
{
    const int nb = ((blockIdx.x & 7) << 6) | (blockIdx.x >> 3);  // XCD swizzle (512)
    const int b = nb >> 7, kt32 = nb & 127;
    const int kbase = kt32 * 32;
    const int tid = threadIdx.x, w = tid >> 6, lane = tid & 63;
    const int l31 = lane & 31, hi = lane >> 5;

    __shared__ unsigned short qsm[8][2][32 * 68];   // 69632 B
    __shared__ float pl[8][32];
    __shared__ float rls[32];

    const unsigned short* kr = Kb + ((size_t)b * LL + kbase + l31) * CC + 8 * hi;
    const bf16x8 ak0 = *(const bf16x8*)(kr);
    const bf16x8 ak1 = *(const bf16x8*)(kr + 16);
    const bf16x8 ak2 = *(const bf16x8*)(kr + 32);
    const bf16x8 ak3 = *(const bf16x8*)(kr + 48);

    const unsigned short* const sQ = Qb + (size_t)b * LL * CC;  // block-uniform base
    const unsigned wqoff = (unsigned)(w * 65536);               // wave's 512-q slab (bytes)
    const int wb = (lane >> 3) * 68 + (lane & 7) * 8;
    unsigned short* const q0b = &qsm[w][0][0];
    unsigned short* const q1b = &qsm[w][1][0];

    u32x4 S0, S1, S2, S3;
    #define QISS(s_) do { \
        const unsigned vo = wqoff + (unsigned)((s_) * 4096 + lane * 16); \
        GLD4(S0, vo, sQ, 0);    GLD4(S1, vo, sQ, 1024); \
        GLD4(S2, vo, sQ, 2048); GLD4(S3, vo, sQ, 3072); \
    } while (0)
    #define QWR(dst) do { \
        unsigned short* _p = (dst) + wb; \
        lds_put(_p, S0);        lds_put(_p + 544, S1); \
        lds_put(_p + 1088, S2); lds_put(_p + 1632, S3); \
    } while (0)

    QISS(0); WAITVM0(); SBAR(); QWR(q0b); QISS(1);

    f32x16 lacc = {};
    for (int s = 0; s < 16; ++s) {
        const unsigned short* qp = ((s & 1) ? q1b : q0b) + l31 * 68 + hi * 8;
        const bf16x8 b0 = lds_frag(qp);
        const bf16x8 b1 = lds_frag(qp + 16);
        const bf16x8 b2 = lds_frag(qp + 32);
        const bf16x8 b3 = lds_frag(qp + 48);
        f32x16 T = {};
        PRIO(1);
        T = MFMA32(ak0, b0, T); T = MFMA32(ak1, b1, T);
        T = MFMA32(ak2, b2, T); T = MFMA32(ak3, b3, T);
        PRIO(0);
        #pragma unroll
        for (int r = 0; r < 16; ++r) lacc[r] += EXP2(T[r] * C2);
        if (s < 15) {
            WAITVM0(); SBAR();
            QWR((s & 1) ? q0b : q1b);
            if (s < 14) QISS(s + 2);
        }
    }
    #undef QISS
    #undef QWR

    #pragma unroll
    for (int r = 0; r < 16; ++r) {
        float v = lacc[r];
        v += __shfl_xor(v, 1);  v += __shfl_xor(v, 2);
        v += __shfl_xor(v, 4);  v += __shfl_xor(v, 8);
        v += __shfl_xor(v, 16);
        lacc[r] = v;
    }
    if (l31 == 0) {
        #pragma unroll
        for (int r = 0; r < 16; ++r)
            pl[w][(r & 3) + 8 * (r >> 2) + 4 * hi] = lacc[r];
    }
    __syncthreads();
    if (tid < 32) {
        float L = 0.f;
        #pragma unroll
        for (int ww = 0; ww < 8; ++ww) L += pl[ww][tid];
        rls[tid] = 1.0f / L;
    }
    __syncthreads();

    {
        unsigned short* vbase = Vt + ((size_t)(b * 128 + kt32)) * 2048;
        const int kin0 = (tid & 7) * 4;
        ushort4 v = *(const ushort4*)(vbase + tid * 4);
        v.x = f2bf(bf2f(v.x) * rls[kin0 + 0]);
        v.y = f2bf(bf2f(v.y) * rls[kin0 + 1]);
        v.z = f2bf(bf2f(v.z) * rls[kin0 + 2]);
        v.w = f2bf(bf2f(v.w) * rls[kin0 + 3]);
        *(ushort4*)(vbase + tid * 4) = v;
    }
}

// ---------------- K3: out = E @ V' + x ----------------
// v13: grid = B*(L/32) = 512 blocks x 512 thr (block = 32 q). Wave w owns
// k in [w*512,(w+1)*512), 16 steps of 32k. Single-buffer wave-private
// K[32][68]+V[64][36] tiles (71.7KB); launch_bounds(512,4) -> 2 blocks/CU
// = 4 waves/SIMD. Zero in-loop barriers; loads held in regs across compute.
__global__ __launch_bounds__(512, 4) void k_out(
    const float* __restrict__ x,
    const unsigned short* __restrict__ Qb, const unsigned short* __restrict__ Kb,
    const unsigned short* __restrict__ Vt,
    float* __restrict__ out)
{
    const int nb = ((blockIdx.x & 7) << 6) | (blockIdx.x >> 3);  // XCD swizzle (512)
    const int b = nb >> 7, qt = nb & 127;
    const int q0 = qt * 32;
    const int tid = threadIdx.x, w = tid >> 6, lane = tid & 63;
    const int l31 = lane & 31, hi = lane >> 5;

    __shared__ unsigned short ksm[8][32 * 68];   // 34816 B
    __shared__ unsigned short vsm[8][64 * 36];   // 36864 B

    // loop-invariant Q B-frags (one-time gather)
    const unsigned short* qr = Qb + ((size_t)b * LL + q0 + l31) * CC + 8 * hi;
    const bf16x8 qb0 = *(const bf16x8*)(qr);
    const bf16x8 qb1 = *(const bf16x8*)(qr + 16);
    const bf16x8 qb2 = *(const bf16x8*)(qr + 32);
    const bf16x8 qb3 = *(const bf16x8*)(qr + 48);

    const unsigned short* const sK = Kb + (size_t)b * LL * CC;        // block-uniform
    const unsigned short* const sV = Vt + (size_t)b * 128 * 2048;     // block-uniform
    const unsigned wkoff = (unsigned)(w * 65536);   // wave's 512-k K slab (bytes)
    const unsigned wvoff = (unsigned)(w * 65536);   // wave's 16 V tiles (bytes)
    const int kwb = (lane >> 3) * 68 + (lane & 7) * 8;
    const int vwb = (lane >> 2) * 36 + (lane & 3) * 8;

    u32x4 K0, K1, K2, K3, V0, V1, V2, V3;
    #define KISS(s_) do { \
        const unsigned vo = wkoff + (unsigned)((s_) * 4096 + lane * 16); \
        GLD4(K0, vo, sK, 0);    GLD4(K1, vo, sK, 1024); \
        GLD4(K2, vo, sK, 2048); GLD4(K3, vo, sK, 3072); \
    } while (0)
    #define VISS(s_) do { \
        const unsigned vo = wvoff + (unsigned)((s_) * 4096 + lane * 16); \
        GLD4(V0, vo, sV, 0);    GLD4(V1, vo, sV, 1024); \
        GLD4(V2, vo, sV, 2048); GLD4(V3, vo, sV, 3072); \
    } while (0)
    #define KWR() do { \
        unsigned short* _p = &ksm[w][0] + kwb; \
        lds_put(_p, K0);        lds_put(_p + 544, K1); \
        lds_put(_p + 1088, K2); lds_put(_p + 1632, K3); \
    } while (0)
    #define VWR() do { \
        unsigned short* _p = &vsm[w][0] + vwb; \
        lds_put(_p, V0);        lds_put(_p + 576, V1); \
        lds_put(_p + 1152, V2); lds_put(_p + 1728, V3); \
    } while (0)

    KISS(0); VISS(0); WAITVM0(); SBAR();
    KWR(); VWR();
    KISS(1); VISS(1);

    f32x16 oacc0 = {}, oacc1 = {};

    for (int s = 0; s < 16; ++s) {
        // ---- S^T (wave's 32-k slice) ----
        const unsigned short* kp = &ksm[w][0] + l31 * 68 + hi * 8;
        const bf16x8 a0 = lds_frag(kp);
        const bf16x8 a1 = lds_frag(kp + 16);
        const bf16x8 a2 = lds_frag(kp + 32);
        const bf16x8 a3 = lds_frag(kp + 48);
        f32x16 T = {};
        T = MFMA32(a0, qb0, T); T = MFMA32(a1, qb1, T);
        T = MFMA32(a2, qb2, T); T = MFMA32(a3, qb3, T);
        // ---- E -> bf16 B-frags via cvt_pk + permlane32_swap ----
        unsigned u0 = cvtpk(EXP2(T[0] * C2),  EXP2(T[1] * C2));
        unsigned u1 = cvtpk(EXP2(T[2] * C2),  EXP2(T[3] * C2));
        unsigned u2 = cvtpk(EXP2(T[4] * C2),  EXP2(T[5] * C2));
        unsigned u3 = cvtpk(EXP2(T[6] * C2),  EXP2(T[7] * C2));
        unsigned u4 = cvtpk(EXP2(T[8] * C2),  EXP2(T[9] * C2));
        unsigned u5 = cvtpk(EXP2(T[10] * C2), EXP2(T[11] * C2));
        unsigned u6 = cvtpk(EXP2(T[12] * C2), EXP2(T[13] * C2));
        unsigned u7 = cvtpk(EXP2(T[14] * C2), EXP2(T[15] * C2));
        asm volatile("s_nop 1");
        asm("v_permlane32_swap_b32 %0, %1" : "+v"(u0), "+v"(u2));
        asm("v_permlane32_swap_b32 %0, %1" : "+v"(u1), "+v"(u3));
        asm("v_permlane32_swap_b32 %0, %1" : "+v"(u4), "+v"(u6));
        asm("v_permlane32_swap_b32 %0, %1" : "+v"(u5), "+v"(u7));
        u32x4 f1, f2;
        f1[0] = u0; f1[1] = u1; f1[2] = u2; f1[3] = u3;
        f2[0] = u4; f2[1] = u5; f2[2] = u6; f2[3] = u7;
        // ---- PV ----
        const unsigned short* vp0 = &vsm[w][0] + l31 * 36 + hi * 8;
        const unsigned short* vp1 = &vsm[w][0] + (32 + l31) * 36 + hi * 8;
        const bf16x8 v00 = lds_frag(vp0);
        const bf16x8 v01 = lds_frag(vp0 + 16);
        const bf16x8 v10 = lds_frag(vp1);
        const bf16x8 v11 = lds_frag(vp1 + 16);
        oacc0 = MFMA32(v00, asbf(f1), oacc0);
        oacc0 = MFMA32(v01, asbf(f2), oacc0);
        oacc1 = MFMA32(v10, asbf(f1), oacc1);
        oacc1 = MFMA32(v11, asbf(f2), oacc1);
        // ---- pipeline maintenance (single buffer: wave-private in-order
        //      LDS; writes alias this step's reads so no hoisting) ----
        if (s < 15) {
            WAITVM0(); SBAR();              // tile s+1 regs arrived
            KWR(); VWR();
            if (s < 14) { KISS(s + 2); VISS(s + 2); }
        }
    }
    #undef KISS
    #undef VISS
    #undef KWR
    #undef VWR

    // combine 8 waves' k-split partials (ocomb aliases ksm: 8.7KB <= 34.8KB)
    __syncthreads();
    float* ocomb = (float*)&ksm[0][0];   // [32 q][68]
    for (int i = tid; i < 32 * 68; i += 512) ocomb[i] = 0.f;
    __syncthreads();
    #pragma unroll
    for (int r = 0; r < 16; ++r) {
        const int fr = (r & 3) + 8 * (r >> 2) + 4 * hi;
        atomicAdd(&ocomb[l31 * 68 + fr],      oacc0[r]);
        atomicAdd(&ocomb[l31 * 68 + 32 + fr], oacc1[r]);
    }
    __syncthreads();
    {
        const int q = tid >> 4, fc = tid & 15;       // 32 q x 16 float4
        const size_t row = (size_t)b * LL + q0 + q;
        const float4 xv = ((const float4*)(x + row * CC))[fc];
        const float4 ov = *(const float4*)(&ocomb[q * 68 + fc * 4]);
        ((float4*)(out + row * CC))[fc] =
            make_float4(xv.x + ov.x, xv.y + ov.y, xv.z + ov.z, xv.w + ov.w);
    }
}

extern "C" void kernel_launch(void* const* d_in, const int* in_sizes, int n_in,
                              void* d_out, int out_size, void* d_ws, size_t ws_size,
                              hipStream_t stream)
{
    const float* x  = (const float*)d_in[0];
    const float* Wq = (const float*)d_in[1];
    const float* bq = (const float*)d_in[2];
    const float* Wk = (const float*)d_in[3];
    const float* bk = (const float*)d_in[4];
    const float* Wv = (const float*)d_in[5];
    const float* bv = (const float*)d_in[6];
    float* out = (float*)d_out;

    const size_t n = (size_t)BB * LL * CC;
    unsigned short* Qb = (unsigned short*)d_ws;
    unsigned short* Kb = Qb + n;
    unsigned short* Vt = Kb + n;   // [b][kt32(128)][f(64)][kin(32)]

    hipLaunchKernelGGL(k_qkv, dim3(3 * BB * LL / 64), dim3(512), 0, stream,
                       x, Wq, bq, Wk, bk, Wv, bv, Qb, Kb, Vt);
    hipLaunchKernelGGL(k_stats, dim3(BB * (LL / 32)), dim3(512), 0, stream,
                       Qb, Kb, Vt);
    hipLaunchKernelGGL(k_out, dim3(BB * (LL / 32)), dim3(512), 0, stream,
                       x, Qb, Kb, Vt, out);
}

// Round 14
// 91.658 us; speedup vs baseline: 1.1141x; 1.1141x over previous
//
#include <hip/hip_runtime.h>
#include <math.h>

// Attention1D: B=4, L=4096, C=F=64, fp32 in/out.
// scores=(QK^T)/8; softmax over QUERY axis; out = P@V + x = E@(diag(rl)V) + x.
// v14: fragment-tile layout for Qb/Kb/Vt (32-row tiles, [frag][lane]x16B,
// produced by k_qkv) so k_stats/k_out stage via ASYNC global_load_lds
// (linear DMA, zero ds_writes) with counted vmcnt (never 0 in-loop),
// conflict-free [frag][lane] ds_read_b128 frag reads, no in-loop barriers.

#define BB 4
#define LL 4096
#define CC 64
#define C2 0.18033688011112042f  // 0.125 * log2(e)

typedef __attribute__((ext_vector_type(8)))  short bf16x8;
typedef __attribute__((ext_vector_type(4)))  float f32x4;
typedef __attribute__((ext_vector_type(16))) float f32x16;
typedef __attribute__((ext_vector_type(4)))  unsigned int u32x4;

#define MFMA16(a, b, c) __builtin_amdgcn_mfma_f32_16x16x32_bf16(a, b, c, 0, 0, 0)
#define MFMA32(a, b, c) __builtin_amdgcn_mfma_f32_32x32x16_bf16(a, b, c, 0, 0, 0)
#define EXP2(x) __builtin_amdgcn_exp2f(x)

#define GLDS(gp, lp) __builtin_amdgcn_global_load_lds( \
    (const __attribute__((address_space(1))) unsigned int*)(gp), \
    (__attribute__((address_space(3))) unsigned int*)(lp), 16, 0, 0)
#define WAITVM0() asm volatile("s_waitcnt vmcnt(0)" ::: "memory")
#define WAITVM4() asm volatile("s_waitcnt vmcnt(4)" ::: "memory")
#define WAITVM8() asm volatile("s_waitcnt vmcnt(8)" ::: "memory")
#define LGKM0()   asm volatile("s_waitcnt lgkmcnt(0)" ::: "memory")
#define SBAR() __builtin_amdgcn_sched_barrier(0)

static __device__ __forceinline__ bf16x8 asbf(u32x4 v) {
    union { u32x4 a; bf16x8 b; } u; u.a = v; return u.b;
}
static __device__ __forceinline__ unsigned short f2bf(float f) {
    union { float f; unsigned u; } v; v.f = f;
    unsigned r = v.u + 0x7FFFu + ((v.u >> 16) & 1u);
    return (unsigned short)(r >> 16);
}
static __device__ __forceinline__ float bf2f(unsigned short h) {
    union { unsigned u; float f; } v; v.u = ((unsigned)h) << 16; return v.f;
}
static __device__ __forceinline__ bf16x8 pack8(float4 a, float4 b) {
    bf16x8 r;
    r[0] = (short)f2bf(a.x); r[1] = (short)f2bf(a.y);
    r[2] = (short)f2bf(a.z); r[3] = (short)f2bf(a.w);
    r[4] = (short)f2bf(b.x); r[5] = (short)f2bf(b.y);
    r[6] = (short)f2bf(b.z); r[7] = (short)f2bf(b.w);
    return r;
}
static __device__ __forceinline__ unsigned cvtpk(float lo, float hi) {
    unsigned r;
    asm("v_cvt_pk_bf16_f32 %0, %1, %2" : "=v"(r) : "v"(lo), "v"(hi));
    return r;
}

// Fragment-tile layout, per 32-row tile (4KB), shared by Q/K (and V with its
// own row/col meaning):  byte (f*64 + l)*16 + j*2  <->  M[t*32 + (l&31)]
// [f*16 + (l>>5)*8 + j].  Reader lane l, frag f: lds[f*1024 + l*16] (16B).

// ---------------- K1: projections -> fragment-tiled bf16 Q, K, V' ----------------
__global__ __launch_bounds__(512) void k_qkv(
    const float* __restrict__ x,
    const float* __restrict__ Wq, const float* __restrict__ bq,
    const float* __restrict__ Wk, const float* __restrict__ bk,
    const float* __restrict__ Wv, const float* __restrict__ bv,
    unsigned short* __restrict__ Qb, unsigned short* __restrict__ Kb,
    unsigned short* __restrict__ Vt)
{
    __shared__ float Wl[64 * 64];             // 16 KB
    __shared__ unsigned short ldsV[64 * 72];  // 9 KB
    __shared__ unsigned short ldsF[4096];     // 8 KB fragment-order staging
    const int bid = blockIdx.x;
    const int mat = bid % 3;          // 0:Q 1:K 2:V
    const int r0 = (bid / 3) * 64;
    const int tid = threadIdx.x, w = tid >> 6, lane = tid & 63;
    const int c = lane & 15, g = lane >> 4;
    const int rw = (w >> 1) * 16;
    const int c0 = (w & 1) * 32;

    const float* W  = (mat == 0) ? Wq : (mat == 1) ? Wk : Wv;
    const float* bs = (mat == 0) ? bq : (mat == 1) ? bk : bv;

    {   // coalesced W stage
        const float4* wsrc = (const float4*)W;
        float4* wdst = (float4*)Wl;
        wdst[tid] = wsrc[tid];
        wdst[tid + 512] = wsrc[tid + 512];
    }

    const float* xr = x + (size_t)(r0 + rw + c) * CC;
    const bf16x8 ax0 = pack8(((const float4*)xr)[2 * g], ((const float4*)xr)[2 * g + 1]);
    const bf16x8 ax1 = pack8(((const float4*)xr)[8 + 2 * g], ((const float4*)xr)[8 + 2 * g + 1]);
    __syncthreads();

    f32x4 acc0 = {0.f, 0.f, 0.f, 0.f}, acc1 = {0.f, 0.f, 0.f, 0.f};
    {
        const int col = c0 + c;
        bf16x8 b0, b1;
        #pragma unroll
        for (int j = 0; j < 8; ++j) {
            b0[j] = (short)f2bf(Wl[(8 * g + j) * 64 + col]);
            b1[j] = (short)f2bf(Wl[(32 + 8 * g + j) * 64 + col]);
        }
        acc0 = MFMA16(ax0, b0, acc0); acc0 = MFMA16(ax1, b1, acc0);
    }
    {
        const int col = c0 + 16 + c;
        bf16x8 b0, b1;
        #pragma unroll
        for (int j = 0; j < 8; ++j) {
            b0[j] = (short)f2bf(Wl[(8 * g + j) * 64 + col]);
            b1[j] = (short)f2bf(Wl[(32 + 8 * g + j) * 64 + col]);
        }
        acc1 = MFMA16(ax0, b0, acc1); acc1 = MFMA16(ax1, b1, acc1);
    }
    const float bias0 = bs[c0 + c], bias1 = bs[c0 + 16 + c];

    if (mat < 2) {
        // stage into fragment order, then one coalesced 16B write per thread
        #pragma unroll
        for (int r = 0; r < 4; ++r) {
            const int row = rw + 4 * g + r;       // 0..63 within block
            const int tl = row >> 5, lr = row & 31;
            const int col0 = c0 + c;
            ldsF[tl * 2048 + (col0 >> 4) * 512 + (((col0 >> 3) & 1) * 32 + lr) * 8 + (col0 & 7)]
                = f2bf(acc0[r] + bias0);
            const int col1 = c0 + 16 + c;
            ldsF[tl * 2048 + (col1 >> 4) * 512 + (((col1 >> 3) & 1) * 32 + lr) * 8 + (col1 & 7)]
                = f2bf(acc1[r] + bias1);
        }
        __syncthreads();
        unsigned short* dst = (mat == 0) ? Qb : Kb;
        *(uint4*)(dst + ((size_t)(r0 >> 5)) * 2048 + tid * 8) =
            *(const uint4*)(ldsF + tid * 8);
    } else {
        #pragma unroll
        for (int r = 0; r < 4; ++r) {
            const int rowin = rw + 4 * g + r;     // k within 64-row group
            ldsV[(c0 + c) * 72 + rowin]      = f2bf(acc0[r] + bias0);
            ldsV[(c0 + 16 + c) * 72 + rowin] = f2bf(acc1[r] + bias1);
        }
        __syncthreads();
        // V fragment-tiles: f = tid>>3, ch = tid&7 -> 16B per thread
        const int b = r0 >> 12, ktb = (r0 & 4095) >> 5;
        const int f = tid >> 3, ch = tid & 7;
        const size_t dtile = (size_t)(b * 128 + ktb + (ch >> 2));
        const size_t didx = dtile * 2048
            + (size_t)(((f >> 5) * 2 + ((ch >> 1) & 1)) * 512
                       + ((ch & 1) * 32 + (f & 31)) * 8);
        *(uint4*)(Vt + didx) = *(const uint4*)(ldsV + f * 72 + ch * 8);
    }
}

// ---------------- K2: column sums -> rescale V-tiles in place ----------------
// grid = B*(L/64) = 256 x 512. Block owns 64 k (2 tiles); wave w owns
// q-slab [w*512,(w+1)*512) = 16 Q tiles. global_load_lds staging, 2-deep,
// counted vmcnt(4); zero in-loop barriers/ds_writes.
__global__ __launch_bounds__(512, 2) void k_stats(
    const unsigned short* __restrict__ Qb, const unsigned short* __restrict__ Kb,
    unsigned short* __restrict__ Vt)
{
    const int nb = ((blockIdx.x & 7) << 5) | (blockIdx.x >> 3);  // XCD swizzle (256)
    const int b = nb >> 6, kt = nb & 63;
    const int tid = threadIdx.x, w = tid >> 6, lane = tid & 63;
    const int l31 = lane & 31, hi = lane >> 5;
    const int w_u = __builtin_amdgcn_readfirstlane(w);

    __shared__ unsigned short qsm[8][2][2048];   // 64 KB
    __shared__ float pl[8][64];
    __shared__ float rls[64];

    // K A-frags, 2 tiles (fragment layout: coalesced per-lane 16B reads)
    const char* Kt = (const char*)Kb + ((size_t)(b * 128 + kt * 2)) * 4096 + lane * 16;
    const bf16x8 akA0 = *(const bf16x8*)(Kt);
    const bf16x8 akA1 = *(const bf16x8*)(Kt + 1024);
    const bf16x8 akA2 = *(const bf16x8*)(Kt + 2048);
    const bf16x8 akA3 = *(const bf16x8*)(Kt + 3072);
    const bf16x8 akB0 = *(const bf16x8*)(Kt + 4096);
    const bf16x8 akB1 = *(const bf16x8*)(Kt + 5120);
    const bf16x8 akB2 = *(const bf16x8*)(Kt + 6144);
    const bf16x8 akB3 = *(const bf16x8*)(Kt + 7168);

    const char* const gQ = (const char*)Qb + ((size_t)(b * 128 + w * 16)) * 4096 + lane * 16;

    #define QISS(s_, buf_) do { \
        const char* _g = gQ + (size_t)(s_) * 4096; \
        char* _l = (char*)&qsm[w_u][buf_][0]; \
        GLDS(_g, _l);              GLDS(_g + 1024, _l + 1024); \
        GLDS(_g + 2048, _l + 2048); GLDS(_g + 3072, _l + 3072); \
    } while (0)

    QISS(0, 0); QISS(1, 1);

    f32x16 laccA = {}, laccB = {};
    #pragma unroll 2
    for (int s = 0; s < 16; ++s) {
        const int buf = s & 1;
        if (s < 15) { WAITVM4(); } else { WAITVM0(); }
        SBAR();
        const char* qp = (const char*)&qsm[w_u][buf][0] + lane * 16;
        const bf16x8 q0 = *(const bf16x8*)(qp);
        const bf16x8 q1 = *(const bf16x8*)(qp + 1024);
        const bf16x8 q2 = *(const bf16x8*)(qp + 2048);
        const bf16x8 q3 = *(const bf16x8*)(qp + 3072);
        LGKM0(); SBAR();                    // frag reads done -> safe to DMA over
        if (s < 14) QISS(s + 2, buf);
        f32x16 TA = {}, TB = {};
        TA = MFMA32(akA0, q0, TA); TA = MFMA32(akA1, q1, TA);
        TA = MFMA32(akA2, q2, TA); TA = MFMA32(akA3, q3, TA);
        TB = MFMA32(akB0, q0, TB); TB = MFMA32(akB1, q1, TB);
        TB = MFMA32(akB2, q2, TB); TB = MFMA32(akB3, q3, TB);
        #pragma unroll
        for (int r = 0; r < 16; ++r) {
            laccA[r] += EXP2(TA[r] * C2);
            laccB[r] += EXP2(TB[r] * C2);
        }
    }
    #undef QISS

    // reduce over q (cols): sum across 32 lanes of each half
    #pragma unroll
    for (int r = 0; r < 16; ++r) {
        float va = laccA[r], vb = laccB[r];
        va += __shfl_xor(va, 1);  vb += __shfl_xor(vb, 1);
        va += __shfl_xor(va, 2);  vb += __shfl_xor(vb, 2);
        va += __shfl_xor(va, 4);  vb += __shfl_xor(vb, 4);
        va += __shfl_xor(va, 8);  vb += __shfl_xor(vb, 8);
        va += __shfl_xor(va, 16); vb += __shfl_xor(vb, 16);
        laccA[r] = va; laccB[r] = vb;
    }
    if (l31 == 0) {
        #pragma unroll
        for (int r = 0; r < 16; ++r) {
            const int kr = (r & 3) + 8 * (r >> 2) + 4 * hi;
            pl[w][kr]      = laccA[r];
            pl[w][32 + kr] = laccB[r];
        }
    }
    __syncthreads();
    if (tid < 64) {
        float L = 0.f;
        #pragma unroll
        for (int ww = 0; ww < 8; ++ww) L += pl[ww][tid];
        rls[tid] = 1.0f / L;
    }
    __syncthreads();

    // rescale the two V fragment-tiles in place
    #pragma unroll
    for (int i = 0; i < 2; ++i) {
        unsigned short* base = Vt + ((size_t)(b * 128 + kt * 2 + i)) * 2048;
        const int frag = tid >> 7, lane16 = (tid & 127) >> 1, j0 = (tid & 1) * 4;
        const int kin = (frag & 1) * 16 + (lane16 >> 5) * 8 + j0;
        ushort4 v = *(const ushort4*)(base + tid * 4);
        v.x = f2bf(bf2f(v.x) * rls[i * 32 + kin + 0]);
        v.y = f2bf(bf2f(v.y) * rls[i * 32 + kin + 1]);
        v.z = f2bf(bf2f(v.z) * rls[i * 32 + kin + 2]);
        v.w = f2bf(bf2f(v.w) * rls[i * 32 + kin + 3]);
        *(ushort4*)(base + tid * 4) = v;
    }
}

// ---------------- K3: out = E @ V' + x ----------------
// grid = B*(L/64) = 256 x 512 (block = 64 q, 2 q-frag sets). Wave w owns
// k-slab [w*512,(w+1)*512) = 16 K/V tiles, 16 steps of 32k. Async
// global_load_lds staging into dbuf [frag][lane] tiles, counted vmcnt(8),
// zero in-loop barriers and zero ds_writes. 16 MFMA / step.
__global__ __launch_bounds__(512, 2) void k_out(
    const float* __restrict__ x,
    const unsigned short* __restrict__ Qb, const unsigned short* __restrict__ Kb,
    const unsigned short* __restrict__ Vt,
    float* __restrict__ out)
{
    const int nb = ((blockIdx.x & 7) << 5) | (blockIdx.x >> 3);  // XCD swizzle (256)
    const int b = nb >> 6, qt = nb & 63;
    const int q0 = qt * 64;
    const int tid = threadIdx.x, w = tid >> 6, lane = tid & 63;
    const int l31 = lane & 31, hi = lane >> 5;
    const int w_u = __builtin_amdgcn_readfirstlane(w);

    __shared__ unsigned short ksm[8][2][2048];   // 64 KB
    __shared__ unsigned short vsm[8][2][2048];   // 64 KB

    // Q B-frags, 2 q-sets, from fragment-tiles (coalesced 16B/lane)
    const char* Qt0 = (const char*)Qb + ((size_t)(b * 128 + qt * 2)) * 4096 + lane * 16;
    const bf16x8 qA0 = *(const bf16x8*)(Qt0);
    const bf16x8 qA1 = *(const bf16x8*)(Qt0 + 1024);
    const bf16x8 qA2 = *(const bf16x8*)(Qt0 + 2048);
    const bf16x8 qA3 = *(const bf16x8*)(Qt0 + 3072);
    const bf16x8 qB0 = *(const bf16x8*)(Qt0 + 4096);
    const bf16x8 qB1 = *(const bf16x8*)(Qt0 + 5120);
    const bf16x8 qB2 = *(const bf16x8*)(Qt0 + 6144);
    const bf16x8 qB3 = *(const bf16x8*)(Qt0 + 7168);

    const char* const gK = (const char*)Kb + ((size_t)(b * 128 + w * 16)) * 4096 + lane * 16;
    const char* const gV = (const char*)Vt + ((size_t)(b * 128 + w * 16)) * 4096 + lane * 16;

    #define ISS(s_, buf_) do { \
        const char* _gk = gK + (size_t)(s_) * 4096; \
        const char* _gv = gV + (size_t)(s_) * 4096; \
        char* _lk = (char*)&ksm[w_u][buf_][0]; \
        char* _lv = (char*)&vsm[w_u][buf_][0]; \
        GLDS(_gk, _lk);              GLDS(_gk + 1024, _lk + 1024); \
        GLDS(_gk + 2048, _lk + 2048); GLDS(_gk + 3072, _lk + 3072); \
        GLDS(_gv, _lv);              GLDS(_gv + 1024, _lv + 1024); \
        GLDS(_gv + 2048, _lv + 2048); GLDS(_gv + 3072, _lv + 3072); \
    } while (0)

    ISS(0, 0); ISS(1, 1);

    f32x16 oA0 = {}, oA1 = {}, oB0 = {}, oB1 = {};

    #pragma unroll 2
    for (int s = 0; s < 16; ++s) {
        const int buf = s & 1;
        if (s < 15) { WAITVM8(); } else { WAITVM0(); }
        SBAR();
        const char* kp = (const char*)&ksm[w_u][buf][0] + lane * 16;
        const char* vp = (const char*)&vsm[w_u][buf][0] + lane * 16;
        const bf16x8 a0  = *(const bf16x8*)(kp);
        const bf16x8 a1  = *(const bf16x8*)(kp + 1024);
        const bf16x8 a2  = *(const bf16x8*)(kp + 2048);
        const bf16x8 a3  = *(const bf16x8*)(kp + 3072);
        const bf16x8 v00 = *(const bf16x8*)(vp);
        const bf16x8 v01 = *(const bf16x8*)(vp + 1024);
        const bf16x8 v10 = *(const bf16x8*)(vp + 2048);
        const bf16x8 v11 = *(const bf16x8*)(vp + 3072);
        LGKM0(); SBAR();                    // frag reads done -> safe to DMA over
        if (s < 14) ISS(s + 2, buf);
        // ---- S^T for both q-sets ----
        f32x16 TA = {}, TB = {};
        TA = MFMA32(a0, qA0, TA); TA = MFMA32(a1, qA1, TA);
        TA = MFMA32(a2, qA2, TA); TA = MFMA32(a3, qA3, TA);
        TB = MFMA32(a0, qB0, TB); TB = MFMA32(a1, qB1, TB);
        TB = MFMA32(a2, qB2, TB); TB = MFMA32(a3, qB3, TB);
        // ---- E -> bf16 B-frags (cvt_pk + permlane32_swap), both sets ----
        unsigned a0u = cvtpk(EXP2(TA[0] * C2),  EXP2(TA[1] * C2));
        unsigned a1u = cvtpk(EXP2(TA[2] * C2),  EXP2(TA[3] * C2));
        unsigned a2u = cvtpk(EXP2(TA[4] * C2),  EXP2(TA[5] * C2));
        unsigned a3u = cvtpk(EXP2(TA[6] * C2),  EXP2(TA[7] * C2));
        unsigned a4u = cvtpk(EXP2(TA[8] * C2),  EXP2(TA[9] * C2));
        unsigned a5u = cvtpk(EXP2(TA[10] * C2), EXP2(TA[11] * C2));
        unsigned a6u = cvtpk(EXP2(TA[12] * C2), EXP2(TA[13] * C2));
        unsigned a7u = cvtpk(EXP2(TA[14] * C2), EXP2(TA[15] * C2));
        unsigned b0u = cvtpk(EXP2(TB[0] * C2),  EXP2(TB[1] * C2));
        unsigned b1u = cvtpk(EXP2(TB[2] * C2),  EXP2(TB[3] * C2));
        unsigned b2u = cvtpk(EXP2(TB[4] * C2),  EXP2(TB[5] * C2));
        unsigned b3u = cvtpk(EXP2(TB[6] * C2),  EXP2(TB[7] * C2));
        unsigned b4u = cvtpk(EXP2(TB[8] * C2),  EXP2(TB[9] * C2));
        unsigned b5u = cvtpk(EXP2(TB[10] * C2), EXP2(TB[11] * C2));
        unsigned b6u = cvtpk(EXP2(TB[12] * C2), EXP2(TB[13] * C2));
        unsigned b7u = cvtpk(EXP2(TB[14] * C2), EXP2(TB[15] * C2));
        asm volatile("s_nop 1");
        asm("v_permlane32_swap_b32 %0, %1" : "+v"(a0u), "+v"(a2u));
        asm("v_permlane32_swap_b32 %0, %1" : "+v"(a1u), "+v"(a3u));
        asm("v_permlane32_swap_b32 %0, %1" : "+v"(a4u), "+v"(a6u));
        asm("v_permlane32_swap_b32 %0, %1" : "+v"(a5u), "+v"(a7u));
        asm("v_permlane32_swap_b32 %0, %1" : "+v"(b0u), "+v"(b2u));
        asm("v_permlane32_swap_b32 %0, %1" : "+v"(b1u), "+v"(b3u));
        asm("v_permlane32_swap_b32 %0, %1" : "+v"(b4u), "+v"(b6u));
        asm("v_permlane32_swap_b32 %0, %1" : "+v"(b5u), "+v"(b7u));
        u32x4 fA1, fA2, fB1, fB2;
        fA1[0] = a0u; fA1[1] = a1u; fA1[2] = a2u; fA1[3] = a3u;
        fA2[0] = a4u; fA2[1] = a5u; fA2[2] = a6u; fA2[3] = a7u;
        fB1[0] = b0u; fB1[1] = b1u; fB1[2] = b2u; fB1[3] = b3u;
        fB2[0] = b4u; fB2[1] = b5u; fB2[2] = b6u; fB2[3] = b7u;
        // ---- PV for both q-sets ----
        oA0 = MFMA32(v00, asbf(fA1), oA0);
        oA0 = MFMA32(v01, asbf(fA2), oA0);
        oA1 = MFMA32(v10, asbf(fA1), oA1);
        oA1 = MFMA32(v11, asbf(fA2), oA1);
        oB0 = MFMA32(v00, asbf(fB1), oB0);
        oB0 = MFMA32(v01, asbf(fB2), oB0);
        oB1 = MFMA32(v10, asbf(fB1), oB1);
        oB1 = MFMA32(v11, asbf(fB2), oB1);
    }
    #undef ISS

    // combine 8 waves' k-split partials (ocomb aliases ksm; all DMA drained)
    __syncthreads();
    float* ocomb = (float*)&ksm[0][0][0];   // [64 q][68]
    for (int i = tid; i < 64 * 68; i += 512) ocomb[i] = 0.f;
    __syncthreads();
    #pragma unroll
    for (int r = 0; r < 16; ++r) {
        const int fr = (r & 3) + 8 * (r >> 2) + 4 * hi;
        atomicAdd(&ocomb[l31 * 68 + fr],             oA0[r]);
        atomicAdd(&ocomb[l31 * 68 + 32 + fr],        oA1[r]);
        atomicAdd(&ocomb[(32 + l31) * 68 + fr],      oB0[r]);
        atomicAdd(&ocomb[(32 + l31) * 68 + 32 + fr], oB1[r]);
    }
    __syncthreads();
    {
        const int q = tid >> 3, f8 = (tid & 7) * 8;   // 64 q x 8 f-chunks
        const size_t row = (size_t)b * LL + q0 + q;
        const float4 xv0 = ((const float4*)(x + row * CC))[f8 >> 2];
        const float4 xv1 = ((const float4*)(x + row * CC))[(f8 >> 2) + 1];
        const float4 ov0 = *(const float4*)(&ocomb[q * 68 + f8]);
        const float4 ov1 = *(const float4*)(&ocomb[q * 68 + f8 + 4]);
        ((float4*)(out + row * CC))[f8 >> 2] =
            make_float4(xv0.x + ov0.x, xv0.y + ov0.y, xv0.z + ov0.z, xv0.w + ov0.w);
        ((float4*)(out + row * CC))[(f8 >> 2) + 1] =
            make_float4(xv1.x + ov1.x, xv1.y + ov1.y, xv1.z + ov1.z, xv1.w + ov1.w);
    }
}

extern "C" void kernel_launch(void* const* d_in, const int* in_sizes, int n_in,
                              void* d_out, int out_size, void* d_ws, size_t ws_size,
                              hipStream_t stream)
{
    const float* x  = (const float*)d_in[0];
    const float* Wq = (const float*)d_in[1];
    const float* bq = (const float*)d_in[2];
    const float* Wk = (const float*)d_in[3];
    const float* bk = (const float*)d_in[4];
    const float* Wv = (const float*)d_in[5];
    const float* bv = (const float*)d_in[6];
    float* out = (float*)d_out;

    const size_t n = (size_t)BB * LL * CC;
    unsigned short* Qb = (unsigned short*)d_ws;   // fragment-tiled [512 tiles][4KB]
    unsigned short* Kb = Qb + n;
    unsigned short* Vt = Kb + n;

    hipLaunchKernelGGL(k_qkv, dim3(3 * BB * LL / 64), dim3(512), 0, stream,
                       x, Wq, bq, Wk, bk, Wv, bv, Qb, Kb, Vt);
    hipLaunchKernelGGL(k_stats, dim3(BB * (LL / 64)), dim3(512), 0, stream,
                       Qb, Kb, Vt);
    hipLaunchKernelGGL(k_out, dim3(BB * (LL / 64)), dim3(512), 0, stream,
                       x, Qb, Kb, Vt, out);
}

// Round 15
// 88.662 us; speedup vs baseline: 1.1517x; 1.0338x over previous
//
#include <hip/hip_runtime.h>
#include <math.h>

// Attention1D: B=4, L=4096, C=F=64, fp32 in/out.
// scores=(QK^T)/8; softmax over QUERY axis; out = P@V + x = E@(diag(rl)V) + x.
// v15: ZERO-LDS inner loops. Q/K/V are fragment-tiled (32-row 4KB tiles,
// [frag][lane]x16B, from k_qkv) so each MFMA fragment is ONE coalesced
// global_load_dwordx4 (base + tile*4096 + lane*16) straight into registers.
// 2-set software pipeline with split counted vmcnt (r6-proven), no barriers,
// no ds_read/ds_write, no lgkm drains. LDS only for the output combine.

#define BB 4
#define LL 4096
#define CC 64
#define C2 0.18033688011112042f  // 0.125 * log2(e)

typedef __attribute__((ext_vector_type(8)))  short bf16x8;
typedef __attribute__((ext_vector_type(4)))  float f32x4;
typedef __attribute__((ext_vector_type(16))) float f32x16;
typedef __attribute__((ext_vector_type(4)))  unsigned int u32x4;

#define MFMA16(a, b, c) __builtin_amdgcn_mfma_f32_16x16x32_bf16(a, b, c, 0, 0, 0)
#define MFMA32(a, b, c) __builtin_amdgcn_mfma_f32_32x32x16_bf16(a, b, c, 0, 0, 0)
#define EXP2(x) __builtin_amdgcn_exp2f(x)

#define GLD4(dst, voff, base, imm) \
    asm volatile("global_load_dwordx4 %0, %1, %2 offset:%c3" \
                 : "=v"(dst) : "v"(voff), "s"(base), "i"(imm))
#define WAITVM(n) asm volatile("s_waitcnt vmcnt(" #n ")")
#define WAITVM0() asm volatile("s_waitcnt vmcnt(0)" ::: "memory")
#define SBAR() __builtin_amdgcn_sched_barrier(0)

static __device__ __forceinline__ bf16x8 asbf(u32x4 v) {
    union { u32x4 a; bf16x8 b; } u; u.a = v; return u.b;
}
static __device__ __forceinline__ unsigned short f2bf(float f) {
    union { float f; unsigned u; } v; v.f = f;
    unsigned r = v.u + 0x7FFFu + ((v.u >> 16) & 1u);
    return (unsigned short)(r >> 16);
}
static __device__ __forceinline__ float bf2f(unsigned short h) {
    union { unsigned u; float f; } v; v.u = ((unsigned)h) << 16; return v.f;
}
static __device__ __forceinline__ bf16x8 pack8(float4 a, float4 b) {
    bf16x8 r;
    r[0] = (short)f2bf(a.x); r[1] = (short)f2bf(a.y);
    r[2] = (short)f2bf(a.z); r[3] = (short)f2bf(a.w);
    r[4] = (short)f2bf(b.x); r[5] = (short)f2bf(b.y);
    r[6] = (short)f2bf(b.z); r[7] = (short)f2bf(b.w);
    return r;
}
static __device__ __forceinline__ unsigned cvtpk(float lo, float hi) {
    unsigned r;
    asm("v_cvt_pk_bf16_f32 %0, %1, %2" : "=v"(r) : "v"(lo), "v"(hi));
    return r;
}

// ---------------- K1: projections -> fragment-tiled bf16 Q, K, V ----------------
// (unchanged from v14 — verified)
__global__ __launch_bounds__(512) void k_qkv(
    const float* __restrict__ x,
    const float* __restrict__ Wq, const float* __restrict__ bq,
    const float* __restrict__ Wk, const float* __restrict__ bk,
    const float* __restrict__ Wv, const float* __restrict__ bv,
    unsigned short* __restrict__ Qb, unsigned short* __restrict__ Kb,
    unsigned short* __restrict__ Vt)
{
    __shared__ float Wl[64 * 64];
    __shared__ unsigned short ldsV[64 * 72];
    __shared__ unsigned short ldsF[4096];
    const int bid = blockIdx.x;
    const int mat = bid % 3;          // 0:Q 1:K 2:V
    const int r0 = (bid / 3) * 64;
    const int tid = threadIdx.x, w = tid >> 6, lane = tid & 63;
    const int c = lane & 15, g = lane >> 4;
    const int rw = (w >> 1) * 16;
    const int c0 = (w & 1) * 32;

    const float* W  = (mat == 0) ? Wq : (mat == 1) ? Wk : Wv;
    const float* bs = (mat == 0) ? bq : (mat == 1) ? bk : bv;

    {   // coalesced W stage
        const float4* wsrc = (const float4*)W;
        float4* wdst = (float4*)Wl;
        wdst[tid] = wsrc[tid];
        wdst[tid + 512] = wsrc[tid + 512];
    }

    const float* xr = x + (size_t)(r0 + rw + c) * CC;
    const bf16x8 ax0 = pack8(((const float4*)xr)[2 * g], ((const float4*)xr)[2 * g + 1]);
    const bf16x8 ax1 = pack8(((const float4*)xr)[8 + 2 * g], ((const float4*)xr)[8 + 2 * g + 1]);
    __syncthreads();

    f32x4 acc0 = {0.f, 0.f, 0.f, 0.f}, acc1 = {0.f, 0.f, 0.f, 0.f};
    {
        const int col = c0 + c;
        bf16x8 b0, b1;
        #pragma unroll
        for (int j = 0; j < 8; ++j) {
            b0[j] = (short)f2bf(Wl[(8 * g + j) * 64 + col]);
            b1[j] = (short)f2bf(Wl[(32 + 8 * g + j) * 64 + col]);
        }
        acc0 = MFMA16(ax0, b0, acc0); acc0 = MFMA16(ax1, b1, acc0);
    }
    {
        const int col = c0 + 16 + c;
        bf16x8 b0, b1;
        #pragma unroll
        for (int j = 0; j < 8; ++j) {
            b0[j] = (short)f2bf(Wl[(8 * g + j) * 64 + col]);
            b1[j] = (short)f2bf(Wl[(32 + 8 * g + j) * 64 + col]);
        }
        acc1 = MFMA16(ax0, b0, acc1); acc1 = MFMA16(ax1, b1, acc1);
    }
    const float bias0 = bs[c0 + c], bias1 = bs[c0 + 16 + c];

    if (mat < 2) {
        #pragma unroll
        for (int r = 0; r < 4; ++r) {
            const int row = rw + 4 * g + r;
            const int tl = row >> 5, lr = row & 31;
            const int col0 = c0 + c;
            ldsF[tl * 2048 + (col0 >> 4) * 512 + (((col0 >> 3) & 1) * 32 + lr) * 8 + (col0 & 7)]
                = f2bf(acc0[r] + bias0);
            const int col1 = c0 + 16 + c;
            ldsF[tl * 2048 + (col1 >> 4) * 512 + (((col1 >> 3) & 1) * 32 + lr) * 8 + (col1 & 7)]
                = f2bf(acc1[r] + bias1);
        }
        __syncthreads();
        unsigned short* dst = (mat == 0) ? Qb : Kb;
        *(uint4*)(dst + ((size_t)(r0 >> 5)) * 2048 + tid * 8) =
            *(const uint4*)(ldsF + tid * 8);
    } else {
        #pragma unroll
        for (int r = 0; r < 4; ++r) {
            const int rowin = rw + 4 * g + r;
            ldsV[(c0 + c) * 72 + rowin]      = f2bf(acc0[r] + bias0);
            ldsV[(c0 + 16 + c) * 72 + rowin] = f2bf(acc1[r] + bias1);
        }
        __syncthreads();
        const int b = r0 >> 12, ktb = (r0 & 4095) >> 5;
        const int f = tid >> 3, ch = tid & 7;
        const size_t dtile = (size_t)(b * 128 + ktb + (ch >> 2));
        const size_t didx = dtile * 2048
            + (size_t)(((f >> 5) * 2 + ((ch >> 1) & 1)) * 512
                       + ((ch & 1) * 32 + (f & 31)) * 8);
        *(uint4*)(Vt + didx) = *(const uint4*)(ldsV + f * 72 + ch * 8);
    }
}

// ---------------- K2: column sums -> rescale V-tiles in place ----------------
// grid = B*(L/64) = 256 x 512. Block owns 64 k (2 K tiles); wave w owns
// q-slab of 16 Q tiles. Register-direct frag loads, 2-set pipeline, vmcnt(4),
// zero LDS in loop.
__global__ __launch_bounds__(512, 3) void k_stats(
    const unsigned short* __restrict__ Qb, const unsigned short* __restrict__ Kb,
    unsigned short* __restrict__ Vt)
{
    const int nb = ((blockIdx.x & 7) << 5) | (blockIdx.x >> 3);  // XCD swizzle (256)
    const int b = nb >> 6, kt = nb & 63;
    const int tid = threadIdx.x, w = tid >> 6, lane = tid & 63;
    const int l31 = lane & 31, hi = lane >> 5;

    __shared__ float pl[8][64];
    __shared__ float rls[64];

    // K A-frags, 2 tiles (fragment layout: coalesced per-lane 16B reads)
    const char* Kt = (const char*)Kb + ((size_t)(b * 128 + kt * 2)) * 4096 + lane * 16;
    const bf16x8 akA0 = *(const bf16x8*)(Kt);
    const bf16x8 akA1 = *(const bf16x8*)(Kt + 1024);
    const bf16x8 akA2 = *(const bf16x8*)(Kt + 2048);
    const bf16x8 akA3 = *(const bf16x8*)(Kt + 3072);
    const bf16x8 akB0 = *(const bf16x8*)(Kt + 4096);
    const bf16x8 akB1 = *(const bf16x8*)(Kt + 5120);
    const bf16x8 akB2 = *(const bf16x8*)(Kt + 6144);
    const bf16x8 akB3 = *(const bf16x8*)(Kt + 7168);

    const char* const sQ = (const char*)Qb + (size_t)b * 128 * 4096;  // block-uniform
    const unsigned wqoff = (unsigned)(w * 16 * 4096 + lane * 16);

    u32x4 qA0, qA1, qA2, qA3, qB0, qB1, qB2, qB3;
    #define QISS(P, s_) do { \
        const unsigned vo = wqoff + (unsigned)((s_) * 4096); \
        GLD4(P##0, vo, sQ, 0);    GLD4(P##1, vo, sQ, 1024); \
        GLD4(P##2, vo, sQ, 2048); GLD4(P##3, vo, sQ, 3072); \
    } while (0)

    QISS(qA, 0); QISS(qB, 1);

    f32x16 laccA = {}, laccB = {};
    #define QHALF(P, nsi) do { \
        WAITVM(4); SBAR(); \
        const bf16x8 q0 = asbf(P##0), q1 = asbf(P##1); \
        const bf16x8 q2 = asbf(P##2), q3 = asbf(P##3); \
        f32x16 TA = {}, TB = {}; \
        TA = MFMA32(akA0, q0, TA); TA = MFMA32(akA1, q1, TA); \
        TA = MFMA32(akA2, q2, TA); TA = MFMA32(akA3, q3, TA); \
        TB = MFMA32(akB0, q0, TB); TB = MFMA32(akB1, q1, TB); \
        TB = MFMA32(akB2, q2, TB); TB = MFMA32(akB3, q3, TB); \
        SBAR(); \
        QISS(P, (nsi) & 15); \
        _Pragma("unroll") \
        for (int r = 0; r < 16; ++r) { \
            laccA[r] += EXP2(TA[r] * C2); \
            laccB[r] += EXP2(TB[r] * C2); \
        } \
    } while (0)

    for (int s = 0; s < 16; s += 2) {   // tail issues wrap: in-bounds, unused
        QHALF(qA, s + 2);
        QHALF(qB, s + 3);
    }
    WAITVM0();
    #undef QHALF
    #undef QISS

    // reduce over q (cols): sum across 32 lanes of each half
    #pragma unroll
    for (int r = 0; r < 16; ++r) {
        float va = laccA[r], vb = laccB[r];
        va += __shfl_xor(va, 1);  vb += __shfl_xor(vb, 1);
        va += __shfl_xor(va, 2);  vb += __shfl_xor(vb, 2);
        va += __shfl_xor(va, 4);  vb += __shfl_xor(vb, 4);
        va += __shfl_xor(va, 8);  vb += __shfl_xor(vb, 8);
        va += __shfl_xor(va, 16); vb += __shfl_xor(vb, 16);
        laccA[r] = va; laccB[r] = vb;
    }
    if (l31 == 0) {
        #pragma unroll
        for (int r = 0; r < 16; ++r) {
            const int kr = (r & 3) + 8 * (r >> 2) + 4 * hi;
            pl[w][kr]      = laccA[r];
            pl[w][32 + kr] = laccB[r];
        }
    }
    __syncthreads();
    if (tid < 64) {
        float L = 0.f;
        #pragma unroll
        for (int ww = 0; ww < 8; ++ww) L += pl[ww][tid];
        rls[tid] = 1.0f / L;
    }
    __syncthreads();

    // rescale the two V fragment-tiles in place (layout from v14 — verified)
    #pragma unroll
    for (int i = 0; i < 2; ++i) {
        unsigned short* base = Vt + ((size_t)(b * 128 + kt * 2 + i)) * 2048;
        const int frag = tid >> 7, lane16 = (tid & 127) >> 1, j0 = (tid & 1) * 4;
        const int kin = (frag & 1) * 16 + (lane16 >> 5) * 8 + j0;
        ushort4 v = *(const ushort4*)(base + tid * 4);
        v.x = f2bf(bf2f(v.x) * rls[i * 32 + kin + 0]);
        v.y = f2bf(bf2f(v.y) * rls[i * 32 + kin + 1]);
        v.z = f2bf(bf2f(v.z) * rls[i * 32 + kin + 2]);
        v.w = f2bf(bf2f(v.w) * rls[i * 32 + kin + 3]);
        *(ushort4*)(base + tid * 4) = v;
    }
}

// ---------------- K3: out = E @ V' + x ----------------
// grid = B*(L/64) = 256 x 512 (block = 64 q, 2 q-frag sets). Wave w owns
// k-slab of 16 K/V tiles, 16 steps of 32k. Register-direct frag loads,
// 2-set pipeline with split waits vmcnt(12) (r6-proven), zero LDS in loop.
__global__ __launch_bounds__(512, 2) void k_out(
    const float* __restrict__ x,
    const unsigned short* __restrict__ Qb, const unsigned short* __restrict__ Kb,
    const unsigned short* __restrict__ Vt,
    float* __restrict__ out)
{
    const int nb = ((blockIdx.x & 7) << 5) | (blockIdx.x >> 3);  // XCD swizzle (256)
    const int b = nb >> 6, qt = nb & 63;
    const int q0 = qt * 64;
    const int tid = threadIdx.x, w = tid >> 6, lane = tid & 63;
    const int l31 = lane & 31, hi = lane >> 5;

    __shared__ float ocomb[64 * 68];   // 17.4 KB (combine only)

    // Q B-frags, 2 q-sets, from fragment-tiles (coalesced 16B/lane)
    const char* Qt0 = (const char*)Qb + ((size_t)(b * 128 + qt * 2)) * 4096 + lane * 16;
    const bf16x8 qA0 = *(const bf16x8*)(Qt0);
    const bf16x8 qA1 = *(const bf16x8*)(Qt0 + 1024);
    const bf16x8 qA2 = *(const bf16x8*)(Qt0 + 2048);
    const bf16x8 qA3 = *(const bf16x8*)(Qt0 + 3072);
    const bf16x8 qB0 = *(const bf16x8*)(Qt0 + 4096);
    const bf16x8 qB1 = *(const bf16x8*)(Qt0 + 5120);
    const bf16x8 qB2 = *(const bf16x8*)(Qt0 + 6144);
    const bf16x8 qB3 = *(const bf16x8*)(Qt0 + 7168);

    const char* const sK = (const char*)Kb + (size_t)b * 128 * 4096;  // block-uniform
    const char* const sV = (const char*)Vt + (size_t)b * 128 * 4096;  // block-uniform
    const unsigned wOff = (unsigned)(w * 16 * 4096 + lane * 16);

    u32x4 Ak0, Ak1, Ak2, Ak3, Av0, Av1, Av2, Av3;
    u32x4 Bk0, Bk1, Bk2, Bk3, Bv0, Bv1, Bv2, Bv3;

    #define KISS(P, s_) do { \
        const unsigned vo = wOff + (unsigned)((s_) * 4096); \
        GLD4(P##k0, vo, sK, 0);    GLD4(P##k1, vo, sK, 1024); \
        GLD4(P##k2, vo, sK, 2048); GLD4(P##k3, vo, sK, 3072); \
    } while (0)
    #define VISS(P, s_) do { \
        const unsigned vo = wOff + (unsigned)((s_) * 4096); \
        GLD4(P##v0, vo, sV, 0);    GLD4(P##v1, vo, sV, 1024); \
        GLD4(P##v2, vo, sV, 2048); GLD4(P##v3, vo, sV, 3072); \
    } while (0)

    KISS(A, 0); VISS(A, 0);
    KISS(B, 1); VISS(B, 1);

    f32x16 oA0 = {}, oA1 = {}, oB0 = {}, oB1 = {};

    #define OHALF(P, nsi) do { \
        WAITVM(12); SBAR(); \
        const bf16x8 a0 = asbf(P##k0), a1 = asbf(P##k1); \
        const bf16x8 a2 = asbf(P##k2), a3 = asbf(P##k3); \
        f32x16 TA = {}, TB = {}; \
        TA = MFMA32(a0, qA0, TA); TA = MFMA32(a1, qA1, TA); \
        TA = MFMA32(a2, qA2, TA); TA = MFMA32(a3, qA3, TA); \
        TB = MFMA32(a0, qB0, TB); TB = MFMA32(a1, qB1, TB); \
        TB = MFMA32(a2, qB2, TB); TB = MFMA32(a3, qB3, TB); \
        SBAR(); \
        KISS(P, (nsi) & 15); \
        unsigned u0 = cvtpk(EXP2(TA[0] * C2),  EXP2(TA[1] * C2)); \
        unsigned u1 = cvtpk(EXP2(TA[2] * C2),  EXP2(TA[3] * C2)); \
        unsigned u2 = cvtpk(EXP2(TA[4] * C2),  EXP2(TA[5] * C2)); \
        unsigned u3 = cvtpk(EXP2(TA[6] * C2),  EXP2(TA[7] * C2)); \
        unsigned u4 = cvtpk(EXP2(TA[8] * C2),  EXP2(TA[9] * C2)); \
        unsigned u5 = cvtpk(EXP2(TA[10] * C2), EXP2(TA[11] * C2)); \
        unsigned u6 = cvtpk(EXP2(TA[12] * C2), EXP2(TA[13] * C2)); \
        unsigned u7 = cvtpk(EXP2(TA[14] * C2), EXP2(TA[15] * C2)); \
        unsigned w0 = cvtpk(EXP2(TB[0] * C2),  EXP2(TB[1] * C2)); \
        unsigned w1 = cvtpk(EXP2(TB[2] * C2),  EXP2(TB[3] * C2)); \
        unsigned w2 = cvtpk(EXP2(TB[4] * C2),  EXP2(TB[5] * C2)); \
        unsigned w3 = cvtpk(EXP2(TB[6] * C2),  EXP2(TB[7] * C2)); \
        unsigned w4 = cvtpk(EXP2(TB[8] * C2),  EXP2(TB[9] * C2)); \
        unsigned w5 = cvtpk(EXP2(TB[10] * C2), EXP2(TB[11] * C2)); \
        unsigned w6 = cvtpk(EXP2(TB[12] * C2), EXP2(TB[13] * C2)); \
        unsigned w7 = cvtpk(EXP2(TB[14] * C2), EXP2(TB[15] * C2)); \
        asm volatile("s_nop 1"); \
        asm("v_permlane32_swap_b32 %0, %1" : "+v"(u0), "+v"(u2)); \
        asm("v_permlane32_swap_b32 %0, %1" : "+v"(u1), "+v"(u3)); \
        asm("v_permlane32_swap_b32 %0, %1" : "+v"(u4), "+v"(u6)); \
        asm("v_permlane32_swap_b32 %0, %1" : "+v"(u5), "+v"(u7)); \
        asm("v_permlane32_swap_b32 %0, %1" : "+v"(w0), "+v"(w2)); \
        asm("v_permlane32_swap_b32 %0, %1" : "+v"(w1), "+v"(w3)); \
        asm("v_permlane32_swap_b32 %0, %1" : "+v"(w4), "+v"(w6)); \
        asm("v_permlane32_swap_b32 %0, %1" : "+v"(w5), "+v"(w7)); \
        u32x4 fA1, fA2, fB1, fB2; \
        fA1[0] = u0; fA1[1] = u1; fA1[2] = u2; fA1[3] = u3; \
        fA2[0] = u4; fA2[1] = u5; fA2[2] = u6; fA2[3] = u7; \
        fB1[0] = w0; fB1[1] = w1; fB1[2] = w2; fB1[3] = w3; \
        fB2[0] = w4; fB2[1] = w5; fB2[2] = w6; fB2[3] = w7; \
        WAITVM(12); SBAR(); \
        const bf16x8 v00 = asbf(P##v0), v01 = asbf(P##v1); \
        const bf16x8 v10 = asbf(P##v2), v11 = asbf(P##v3); \
        oA0 = MFMA32(v00, asbf(fA1), oA0); \
        oA0 = MFMA32(v01, asbf(fA2), oA0); \
        oA1 = MFMA32(v10, asbf(fA1), oA1); \
        oA1 = MFMA32(v11, asbf(fA2), oA1); \
        oB0 = MFMA32(v00, asbf(fB1), oB0); \
        oB0 = MFMA32(v01, asbf(fB2), oB0); \
        oB1 = MFMA32(v10, asbf(fB1), oB1); \
        oB1 = MFMA32(v11, asbf(fB2), oB1); \
        SBAR(); \
        VISS(P, (nsi) & 15); \
    } while (0)

    for (int s = 0; s < 16; s += 2) {   // tail issues wrap: in-bounds, unused
        OHALF(A, s + 2);
        OHALF(B, s + 3);
    }
    WAITVM0();
    #undef OHALF
    #undef KISS
    #undef VISS

    // combine 8 waves' k-split partials
    __syncthreads();
    for (int i = tid; i < 64 * 68; i += 512) ocomb[i] = 0.f;
    __syncthreads();
    #pragma unroll
    for (int r = 0; r < 16; ++r) {
        const int fr = (r & 3) + 8 * (r >> 2) + 4 * hi;
        atomicAdd(&ocomb[l31 * 68 + fr],             oA0[r]);
        atomicAdd(&ocomb[l31 * 68 + 32 + fr],        oA1[r]);
        atomicAdd(&ocomb[(32 + l31) * 68 + fr],      oB0[r]);
        atomicAdd(&ocomb[(32 + l31) * 68 + 32 + fr], oB1[r]);
    }
    __syncthreads();
    {
        const int q = tid >> 3, f8 = (tid & 7) * 8;   // 64 q x 8 f-chunks
        const size_t row = (size_t)b * LL + q0 + q;
        const float4 xv0 = ((const float4*)(x + row * CC))[f8 >> 2];
        const float4 xv1 = ((const float4*)(x + row * CC))[(f8 >> 2) + 1];
        const float4 ov0 = *(const float4*)(&ocomb[q * 68 + f8]);
        const float4 ov1 = *(const float4*)(&ocomb[q * 68 + f8 + 4]);
        ((float4*)(out + row * CC))[f8 >> 2] =
            make_float4(xv0.x + ov0.x, xv0.y + ov0.y, xv0.z + ov0.z, xv0.w + ov0.w);
        ((float4*)(out + row * CC))[(f8 >> 2) + 1] =
            make_float4(xv1.x + ov1.x, xv1.y + ov1.y, xv1.z + ov1.z, xv1.w + ov1.w);
    }
}

extern "C" void kernel_launch(void* const* d_in, const int* in_sizes, int n_in,
                              void* d_out, int out_size, void* d_ws, size_t ws_size,
                              hipStream_t stream)
{
    const float* x  = (const float*)d_in[0];
    const float* Wq = (const float*)d_in[1];
    const float* bq = (const float*)d_in[2];
    const float* Wk = (const float*)d_in[3];
    const float* bk = (const float*)d_in[4];
    const float* Wv = (const float*)d_in[5];
    const float* bv = (const float*)d_in[6];
    float* out = (float*)d_out;

    const size_t n = (size_t)BB * LL * CC;
    unsigned short* Qb = (unsigned short*)d_ws;   // fragment-tiled [512 tiles][4KB]
    unsigned short* Kb = Qb + n;
    unsigned short* Vt = Kb + n;

    hipLaunchKernelGGL(k_qkv, dim3(3 * BB * LL / 64), dim3(512), 0, stream,
                       x, Wq, bq, Wk, bk, Wv, bv, Qb, Kb, Vt);
    hipLaunchKernelGGL(k_stats, dim3(BB * (LL / 64)), dim3(512), 0, stream,
                       Qb, Kb, Vt);
    hipLaunchKernelGGL(k_out, dim3(BB * (LL / 64)), dim3(512), 0, stream,
                       x, Qb, Kb, Vt, out);
}